// Round 1
// baseline (16909.622 us; speedup 1.0000x reference)
//
#include <hip/hip_runtime.h>
#include <math.h>

// EMMA_38792144617759 — fp32, phase-1-only simulation (t<32), 8 XCD-local groups.
//
// Key reduction: lm depends only on M frozen after step 31; DEQ memory read is
// zero for t<32; lp is dead. So we simulate only steps 0..31, record v_pred
// snapshots at write steps, build M once with closed-form decay, then do the
// top-k read + logits.

#define NGRP 8
#define WPG  32

// ---- workspace float offsets (wsF = d_ws + 16KB; first 16KB is int region) ----
#define OF_SCALE  0
#define OF_DFAC   32
#define OF_RNV    64        // 1024: 1/max(||value_W row||,eps)
#define OF_TOPW   1088      // 32*16 softmax weights
#define OF_SCORES 1600      // 32*4096
#define OF_Z      132672    // 2*32*512 (double-buffered z)
#define OF_T      165440    // 32*1024 tanh activations
#define OF_CP     198208    // 32*1024 c_pre = x@W1x + b1
#define OF_G      230976    // 32*512 liquid gate pre-act
#define OF_TAU    247360    // 32*512 liquid tau pre-act
#define OF_H      263744    // 32*512 h state
#define OF_ZS     280128    // 32*512 z snapshot at write step
#define OF_HS     296512    // 32*512 h snapshot
#define OF_M      312896    // 4096*256 memory matrix
// total = 1361472 floats (~5.2MB) + 16KB ints
// int region: wsI[g*32]=barrier cnt, wsI[1024+g*32]=barrier flag, wsI[2048+b*16+j]=top_i

__device__ __forceinline__ float softplusf_(float x){ return x > 20.f ? x : log1pf(expf(x)); }

// group barrier: monotonic count + epoch flag; agent scope so correctness does
// not depend on the blockIdx->XCD mapping.
__device__ __forceinline__ void gbar(int* cnt, int* flg, int& epoch){
  __syncthreads();
  epoch++;
  if (threadIdx.x == 0){
    int prev = __hip_atomic_fetch_add(cnt, 1, __ATOMIC_ACQ_REL, __HIP_MEMORY_SCOPE_AGENT);
    if (prev == epoch*WPG - 1){
      __hip_atomic_store(flg, epoch, __ATOMIC_RELEASE, __HIP_MEMORY_SCOPE_AGENT);
    } else {
      while (__hip_atomic_load(flg, __ATOMIC_ACQUIRE, __HIP_MEMORY_SCOPE_AGENT) < epoch){
        __builtin_amdgcn_s_sleep(2);
      }
    }
  }
  __syncthreads();
}

// ---------------- kernel 1a: scores, M zero, value-row norms, misc ----------------
__global__ void __launch_bounds__(256) emma_k1a(
    const int* key_ids, const int* write_pos,
    const float* key_W, const float* value_W, const float* slot_keys,
    const float* lsr, int* wsI, float* wsF)
{
  const int wg = blockIdx.x, tid = threadIdx.x;
  if (wg < 256) {
    // scores[b][chunk*512 .. +512)
    const int b = wg >> 3, chunk = wg & 7;
    __shared__ __align__(16) float s_kv[256];
    __shared__ float red[256];
    float v = key_W[key_ids[b]*256 + tid];
    red[tid] = v*v; __syncthreads();
    for (int st=128; st; st>>=1){ if (tid<st) red[tid]+=red[tid+st]; __syncthreads(); }
    float inv = 1.f/fmaxf(sqrtf(red[0]), 1e-12f);
    s_kv[tid] = v*inv;
    __syncthreads();
    const int lane = tid & 63, wv = tid >> 6;
    float4 kv4 = *(const float4*)(s_kv + lane*4);
    for (int slot = chunk*512 + wv; slot < chunk*512 + 512; slot += 4){
      float4 sk = *(const float4*)(slot_keys + (size_t)slot*256 + lane*4);
      float p = kv4.x*sk.x + kv4.y*sk.y + kv4.z*sk.z + kv4.w*sk.w;
      #pragma unroll
      for (int m=32;m;m>>=1) p += __shfl_xor(p, m, 64);
      if (lane==0) wsF[OF_SCORES + b*4096 + slot] = p;
    }
  } else if (wg < 320) {
    const int j = wg - 256;
    for (int i=tid;i<16384;i+=256) wsF[OF_M + j*16384 + i] = 0.f;
  } else if (wg < 324) {
    const int row = (wg-320)*256 + tid;
    float ss=0.f; const float* r = value_W + (size_t)row*256;
    for (int k=0;k<256;k++){ float x=r[k]; ss += x*x; }
    wsF[OF_RNV + row] = 1.f/fmaxf(sqrtf(ss), 1e-12f);
  } else {
    for (int i=tid;i<2048;i+=256) wsI[i]=0;  // barrier region
    __shared__ int pres[32];
    if (tid<32){ int p=0; for (int bb=0;bb<32;bb++) if (write_pos[bb]==tid) p=1; pres[tid]=p; }
    __syncthreads();
    if (tid<32){
      int wp = write_pos[tid]; float f=1.f;
      for (int s=wp+1;s<32;s++) if (pres[s]) f *= 0.997f;
      wsF[OF_DFAC + tid] = f;
    }
    if (tid==0) wsF[OF_SCALE] = softplusf_(lsr[0]) + 1e-3f;
  }
}

// ---------------- kernel 1b: exact top-16 + softmax per batch row ----------------
__global__ void __launch_bounds__(256) emma_k1b(int* wsI, float* wsF)
{
  const int b = blockIdx.x, tid = threadIdx.x;
  __shared__ float s_sc[4096];
  __shared__ float s_rv[256]; __shared__ int s_ri[256];
  __shared__ float s_tv[16];
  for (int n=tid;n<4096;n+=256) s_sc[n] = wsF[OF_SCORES + b*4096 + n];
  __syncthreads();
  for (int j=0;j<16;j++){
    float bv = -3.0e38f; int bi = 0x7fffffff;
    for (int n=tid;n<4096;n+=256){
      float v = s_sc[n];
      if (v > bv || (v == bv && n < bi)) { bv=v; bi=n; }
    }
    s_rv[tid]=bv; s_ri[tid]=bi; __syncthreads();
    for (int st=128; st; st>>=1){
      if (tid<st){
        float v2=s_rv[tid+st]; int i2=s_ri[tid+st];
        if (v2 > s_rv[tid] || (v2==s_rv[tid] && i2 < s_ri[tid])) { s_rv[tid]=v2; s_ri[tid]=i2; }
      }
      __syncthreads();
    }
    if (tid==0){
      s_tv[j] = s_rv[0];
      wsI[2048 + b*16 + j] = s_ri[0];
      s_sc[s_ri[0]] = -3.0e38f;
    }
    __syncthreads();
  }
  if (tid==0){
    float mx = s_tv[0], sum=0.f, w[16];
    for (int j=0;j<16;j++){ w[j]=expf(s_tv[j]-mx); sum+=w[j]; }
    for (int j=0;j<16;j++) wsF[OF_TOPW + b*16 + j] = w[j]/sum;
  }
}

// ---------------- kernel 2: persistent trajectory kernel (steps 0..31) ----------------
__global__ void __launch_bounds__(256, 1) emma_k2(
    const int* tokens, const int* write_pos,
    const float* embed_W, const float* u_W1, const float* u_b1,
    const float* u_W2, const float* u_b2,
    const float* l_Wi, const float* l_Wh, const float* l_b,
    const float* l_Wti, const float* l_Wth, const float* l_bt,
    const float* h0, int* wsI, float* wsF)
{
  const int g = blockIdx.x & 7;      // group -> XCD (round-robin heuristic; correctness independent)
  const int w = blockIdx.x >> 3;     // wg id within group, 0..31
  const int tid = threadIdx.x;
  int* cnt = wsI + g*32;
  int* flg = wsI + 1024 + g*32;
  int epoch = 0;

  float* Z  = wsF + OF_Z;     // [2][32][512], buf0 = Z
  float* T  = wsF + OF_T;     // [32][1024]
  float* CP = wsF + OF_CP;    // [32][1024]
  float* G  = wsF + OF_G;     // [32][512]
  float* TA = wsF + OF_TAU;   // [32][512]
  float* H  = wsF + OF_H;     // [32][512]
  float* ZS = wsF + OF_ZS;
  float* HS = wsF + OF_HS;

  // ---- preamble: z=0, h=h0, c_pre for step 0 ----
  if (w < 16) {
    int idx = w*256 + tid;
    if (idx < 2048) { int r=idx>>9, c=idx&511; Z[(g*4+r)*512 + c] = 0.f; }
    else { int i2=idx-2048; int r=i2>>9, c=i2&511; H[(g*4+r)*512 + c] = h0[c]; }
  } else {
    int r = tid>>6, b = g*4+r;
    int c = (w-16)*64 + (tid&63);
    int tok = tokens[b*64 + 0];
    const float* xr = embed_W + (size_t)tok*256;
    float a0=0,a1=0,a2=0,a3=0;
    #pragma unroll 4
    for (int k=0;k<256;k+=4){
      float4 xv = *(const float4*)(xr + k);
      a0 += xv.x * u_W1[(512+k+0)*1024 + c];
      a1 += xv.y * u_W1[(512+k+1)*1024 + c];
      a2 += xv.z * u_W1[(512+k+2)*1024 + c];
      a3 += xv.w * u_W1[(512+k+3)*1024 + c];
    }
    CP[b*1024 + c] = u_b1[c] + ((a0+a1)+(a2+a3));
  }
  gbar(cnt, flg, epoch);

  for (int s=0;s<32;s++){
    for (int i=0;i<8;i++){
      float* zc = Z + (i&1)*16384;
      float* zn = Z + ((i&1)^1)*16384;
      // ---- phase A: t = tanh(z@W1z + c_pre); also pre-bias z_next = z + 0.5*b2
      if (tid < 128) {
        int r = tid>>5, b = g*4+r;
        int c = w*32 + (tid&31);
        const float* zr = zc + b*512;
        float a0=0,a1=0,a2=0,a3=0;
        #pragma unroll 4
        for (int k=0;k<512;k+=4){
          float4 zv = *(const float4*)(zr + k);
          a0 += zv.x * u_W1[(k+0)*1024 + c];
          a1 += zv.y * u_W1[(k+1)*1024 + c];
          a2 += zv.z * u_W1[(k+2)*1024 + c];
          a3 += zv.w * u_W1[(k+3)*1024 + c];
        }
        T[b*1024 + c] = tanhf(CP[b*1024 + c] + (a0+a1)+(a2+a3));
      }
      if (tid < 64) {
        int idx = w*64 + tid;
        int r = idx>>9, c = idx&511;
        int b = g*4+r;
        zn[b*512 + c] = zc[b*512 + c] + 0.5f*u_b2[c];
      }
      gbar(cnt, flg, epoch);
      // ---- phase B: z_next += 0.5*(t@W2), split-K 2-way across wgs via atomics
      if (tid < 128) {
        int r = tid>>5, b = g*4+r;
        int c2 = (w&15)*32 + (tid&31);
        int kh = w>>4;
        const float* tr = T + b*1024 + kh*512;
        const float* w2 = u_W2 + kh*512*512;
        float a0=0,a1=0,a2=0,a3=0;
        #pragma unroll 4
        for (int k=0;k<512;k+=4){
          float4 tv = *(const float4*)(tr + k);
          a0 += tv.x * w2[(k+0)*512 + c2];
          a1 += tv.y * w2[(k+1)*512 + c2];
          a2 += tv.z * w2[(k+2)*512 + c2];
          a3 += tv.w * w2[(k+3)*512 + c2];
        }
        atomicAdd(&zn[b*512 + c2], 0.5f*((a0+a1)+(a2+a3)));
      }
      if (i==7 && tid>=128) {  // init liquid pre-act buffers with biases for L1
        int idx = w*128 + (tid-128);
        if (idx < 2048){ int r=idx>>9, c=idx&511; G[(g*4+r)*512+c] = l_b[c]; }
        else { int i2=idx-2048; int r=i2>>9, c=i2&511; TA[(g*4+r)*512+c] = l_bt[c]; }
      }
      gbar(cnt, flg, epoch);
    }
    // ---- L1: liquid gate/tau pre-activations (z@Wi + h@Wh etc), split-K via atomics
    {
      int sub = tid>>7, l = tid&127;        // sub=0 -> gate, sub=1 -> tau
      int r = l>>5, b = g*4+r;
      int c2 = (w&15)*32 + (l&31);
      int kh = w>>4;                         // 0: z-part, 1: h-part
      const float* inrow = (kh==0) ? (Z + b*512) : (H + b*512);
      const float* W = sub ? (kh==0 ? l_Wti : l_Wth) : (kh==0 ? l_Wi : l_Wh);
      float a0=0,a1=0,a2=0,a3=0;
      #pragma unroll 4
      for (int k=0;k<512;k+=4){
        float4 iv = *(const float4*)(inrow + k);
        a0 += iv.x * W[(k+0)*512 + c2];
        a1 += iv.y * W[(k+1)*512 + c2];
        a2 += iv.z * W[(k+2)*512 + c2];
        a3 += iv.w * W[(k+3)*512 + c2];
      }
      atomicAdd(sub ? &TA[b*512+c2] : &G[b*512+c2], (a0+a1)+(a2+a3));
    }
    gbar(cnt, flg, epoch);
    // ---- L2: h update (+snapshots at write step) | c_pre for next step
    if (w < 16) {
      if (tid < 128) {
        int r = tid>>5, b = g*4+r;
        int c2 = w*32 + (tid&31);
        float gv = tanhf(G[b*512+c2]);
        float tv = softplusf_(TA[b*512+c2]) + 1.0f;
        float hv = H[b*512+c2];
        float hn = hv + (gv - hv)/tv;
        H[b*512+c2] = hn;
        if (write_pos[b] == s) { ZS[b*512+c2] = Z[b*512+c2]; HS[b*512+c2] = hn; }
      }
    } else if (s+1 < 32) {
      int r = tid>>6, b = g*4+r;
      int c = (w-16)*64 + (tid&63);
      int tok = tokens[b*64 + s+1];
      const float* xr = embed_W + (size_t)tok*256;
      float a0=0,a1=0,a2=0,a3=0;
      #pragma unroll 4
      for (int k=0;k<256;k+=4){
        float4 xv = *(const float4*)(xr + k);
        a0 += xv.x * u_W1[(512+k+0)*1024 + c];
        a1 += xv.y * u_W1[(512+k+1)*1024 + c];
        a2 += xv.z * u_W1[(512+k+2)*1024 + c];
        a3 += xv.w * u_W1[(512+k+3)*1024 + c];
      }
      CP[b*1024 + c] = u_b1[c] + ((a0+a1)+(a2+a3));
    }
    gbar(cnt, flg, epoch);
  }
}

// ---------------- kernel 3: v_pred + decay-weighted scatter into M ----------------
__global__ void __launch_bounds__(256) emma_k3(const float* z2v_W, const float* z2v_b,
                                               int* wsI, float* wsF)
{
  const int b = blockIdx.x, c = threadIdx.x;
  const float* zs = wsF + OF_ZS + b*512;
  const float* hs = wsF + OF_HS + b*512;
  float acc = z2v_b[c];
  for (int k=0;k<512;k++) acc += zs[k]*z2v_W[k*256 + c];
  for (int k=0;k<512;k++) acc += hs[k]*z2v_W[(512+k)*256 + c];
  __shared__ float red[256];
  red[c]=acc*acc; __syncthreads();
  for (int st=128; st; st>>=1){ if (c<st) red[c]+=red[c+st]; __syncthreads(); }
  float inv = 1.f/fmaxf(sqrtf(red[0]),1e-12f);
  float vp = acc*inv;
  float f = wsF[OF_DFAC + b];
  for (int j=0;j<16;j++){
    int slot = wsI[2048 + b*16 + j];
    float wj = wsF[OF_TOPW + b*16 + j];
    atomicAdd(&wsF[OF_M + (size_t)slot*256 + c], f*wj*vp);
  }
}

// ---------------- kernel 4: v_mem read, normalize, logits ----------------
__global__ void __launch_bounds__(256) emma_k4(const float* value_W, int* wsI, float* wsF,
                                               float* out)
{
  const int b = blockIdx.x, c = threadIdx.x;
  float m = 0.f;
  for (int j=0;j<16;j++){
    int slot = wsI[2048 + b*16 + j];
    m += wsF[OF_TOPW + b*16 + j] * wsF[OF_M + (size_t)slot*256 + c];
  }
  __shared__ float red[256];
  __shared__ float vn[256];
  red[c]=m*m; __syncthreads();
  for (int st=128; st; st>>=1){ if (c<st) red[c]+=red[c+st]; __syncthreads(); }
  float inv = 1.f/fmaxf(sqrtf(red[0]),1e-12f);
  vn[c] = m*inv;
  __syncthreads();
  float scale = wsF[OF_SCALE];
  for (int q=0;q<4;q++){
    int val = q*256 + c;
    const float* row = value_W + (size_t)val*256;
    float d0=0,d1=0,d2=0,d3=0;
    #pragma unroll 4
    for (int k=0;k<256;k+=4){
      float4 rv = *(const float4*)(row + k);
      d0 += vn[k+0]*rv.x; d1 += vn[k+1]*rv.y; d2 += vn[k+2]*rv.z; d3 += vn[k+3]*rv.w;
    }
    out[b*1024 + val] = scale * wsF[OF_RNV + val] * ((d0+d1)+(d2+d3));
  }
}

extern "C" void kernel_launch(void* const* d_in, const int* in_sizes, int n_in,
                              void* d_out, int out_size, void* d_ws, size_t ws_size,
                              hipStream_t stream)
{
  const int*   tokens    = (const int*)  d_in[0];
  const int*   key_ids   = (const int*)  d_in[1];
  const int*   write_pos = (const int*)  d_in[2];
  // d_in[3] query_pos, d_in[4] value_ids: provably unused by logits_main
  const float* embed_W   = (const float*)d_in[5];
  const float* key_W     = (const float*)d_in[6];
  const float* value_W   = (const float*)d_in[7];
  const float* u_W1      = (const float*)d_in[8];
  const float* u_b1      = (const float*)d_in[9];
  const float* u_W2      = (const float*)d_in[10];
  const float* u_b2      = (const float*)d_in[11];
  const float* l_Wi      = (const float*)d_in[12];
  const float* l_Wh      = (const float*)d_in[13];
  const float* l_b       = (const float*)d_in[14];
  const float* l_Wti     = (const float*)d_in[15];
  const float* l_Wth     = (const float*)d_in[16];
  const float* l_bt      = (const float*)d_in[17];
  const float* h0        = (const float*)d_in[18];
  const float* z2v_W     = (const float*)d_in[19];
  const float* z2v_b     = (const float*)d_in[20];
  const float* lsr       = (const float*)d_in[21];
  const float* slot_keys = (const float*)d_in[22];

  int*   wsI = (int*)d_ws;
  float* wsF = (float*)((char*)d_ws + 16384);
  float* out = (float*)d_out;

  hipLaunchKernelGGL(emma_k1a, dim3(325), dim3(256), 0, stream,
                     key_ids, write_pos, key_W, value_W, slot_keys, lsr, wsI, wsF);
  hipLaunchKernelGGL(emma_k1b, dim3(32), dim3(256), 0, stream, wsI, wsF);
  {
    void* args[] = { (void*)&tokens, (void*)&write_pos, (void*)&embed_W, (void*)&u_W1,
                     (void*)&u_b1, (void*)&u_W2, (void*)&u_b2, (void*)&l_Wi, (void*)&l_Wh,
                     (void*)&l_b, (void*)&l_Wti, (void*)&l_Wth, (void*)&l_bt, (void*)&h0,
                     (void*)&wsI, (void*)&wsF };
    hipLaunchCooperativeKernel(reinterpret_cast<void*>(emma_k2), dim3(256), dim3(256),
                               args, 0, stream);
  }
  hipLaunchKernelGGL(emma_k3, dim3(32), dim3(256), 0, stream, z2v_W, z2v_b, wsI, wsF);
  hipLaunchKernelGGL(emma_k4, dim3(32), dim3(256), 0, stream, value_W, wsI, wsF, out);
}

// Round 4
// 10883.009 us; speedup vs baseline: 1.5538x; 1.5538x over previous
//
#include <hip/hip_runtime.h>
#include <math.h>

// EMMA_38792144617759 v4 — BISECT: exact R1-passing compute (per-wg column
// GEMMs, atomicAdd split-K, M-scatter epilogue) with ONLY the barrier changed
// to the fence design (relaxed flag array + one release/acquire agent fence).
// v2/v3 failed bit-identically (deterministic) -> isolate barrier vs new-k2 math.

#define NGRP 8
#define WPG  32

// ---- workspace float offsets (wsF = d_ws + 16KB; first 16KB is int region) ----
#define OF_SCALE  0
#define OF_DFAC   32
#define OF_RNV    64        // 1024: 1/max(||value_W row||,eps)
#define OF_TOPW   1088      // 32*16 softmax weights
#define OF_SCORES 1600      // 32*4096
#define OF_Z      132672    // 2*32*512 (double-buffered z)
#define OF_T      165440    // 32*1024 tanh activations
#define OF_CP     198208    // 32*1024 c_pre = x@W1x + b1
#define OF_G      230976    // 32*512 liquid gate pre-act
#define OF_TAU    247360    // 32*512 liquid tau pre-act
#define OF_H      263744    // 32*512 h state
#define OF_ZS     280128    // 32*512 z snapshot at write step
#define OF_HS     296512    // 32*512 h snapshot
#define OF_M      312896    // 4096*256 memory matrix
// total = 1361472 floats (~5.2MB) + 16KB ints
// int region: wsI[g*32+w]=barrier flag, wsI[2048+b*16+j]=top_i

__device__ __forceinline__ float softplusf_(float x){ return x > 20.f ? x : log1pf(expf(x)); }

// Fence barrier: producer = release fence (wb L2) + relaxed flag store;
// consumer = relaxed poll of all 32 flags + ONE acquire fence (inv L1/L2).
// Correct per the AMDGPU memory model regardless of wg->XCD placement.
__device__ __forceinline__ void gbar(int* flags, int w, int& epoch){
  __syncthreads();                       // vmcnt(0): this wg's stores are in L2
  epoch++;
  if (threadIdx.x == 0){
    __builtin_amdgcn_fence(__ATOMIC_RELEASE, "agent");
    __hip_atomic_store(&flags[w], epoch, __ATOMIC_RELAXED, __HIP_MEMORY_SCOPE_AGENT);
  }
  if (threadIdx.x < 32){
    while (__hip_atomic_load(&flags[threadIdx.x], __ATOMIC_RELAXED,
                             __HIP_MEMORY_SCOPE_AGENT) < epoch)
      __builtin_amdgcn_s_sleep(1);
    __builtin_amdgcn_fence(__ATOMIC_ACQUIRE, "agent");
  }
  __syncthreads();
}

// ---------------- kernel 1a: scores, M zero, value-row norms, misc ----------------
__global__ void __launch_bounds__(256) emma_k1a(
    const int* key_ids, const int* write_pos,
    const float* key_W, const float* value_W, const float* slot_keys,
    const float* lsr, int* wsI, float* wsF)
{
  const int wg = blockIdx.x, tid = threadIdx.x;
  if (wg < 256) {
    // scores[b][chunk*512 .. +512)
    const int b = wg >> 3, chunk = wg & 7;
    __shared__ __align__(16) float s_kv[256];
    __shared__ float red[256];
    float v = key_W[key_ids[b]*256 + tid];
    red[tid] = v*v; __syncthreads();
    for (int st=128; st; st>>=1){ if (tid<st) red[tid]+=red[tid+st]; __syncthreads(); }
    float inv = 1.f/fmaxf(sqrtf(red[0]), 1e-12f);
    s_kv[tid] = v*inv;
    __syncthreads();
    const int lane = tid & 63, wv = tid >> 6;
    float4 kv4 = *(const float4*)(s_kv + lane*4);
    for (int slot = chunk*512 + wv; slot < chunk*512 + 512; slot += 4){
      float4 sk = *(const float4*)(slot_keys + (size_t)slot*256 + lane*4);
      float p = kv4.x*sk.x + kv4.y*sk.y + kv4.z*sk.z + kv4.w*sk.w;
      #pragma unroll
      for (int m=32;m;m>>=1) p += __shfl_xor(p, m, 64);
      if (lane==0) wsF[OF_SCORES + b*4096 + slot] = p;
    }
  } else if (wg < 320) {
    const int j = wg - 256;
    for (int i=tid;i<16384;i+=256) wsF[OF_M + j*16384 + i] = 0.f;
  } else if (wg < 324) {
    const int row = (wg-320)*256 + tid;
    float ss=0.f; const float* r = value_W + (size_t)row*256;
    for (int k=0;k<256;k++){ float x=r[k]; ss += x*x; }
    wsF[OF_RNV + row] = 1.f/fmaxf(sqrtf(ss), 1e-12f);
  } else {
    for (int i=tid;i<2048;i+=256) wsI[i]=0;  // barrier flags region
    __shared__ int pres[32];
    if (tid<32){ int p=0; for (int bb=0;bb<32;bb++) if (write_pos[bb]==tid) p=1; pres[tid]=p; }
    __syncthreads();
    if (tid<32){
      int wp = write_pos[tid]; float f=1.f;
      for (int s=wp+1;s<32;s++) if (pres[s]) f *= 0.997f;
      wsF[OF_DFAC + tid] = f;
    }
    if (tid==0) wsF[OF_SCALE] = softplusf_(lsr[0]) + 1e-3f;
  }
}

// ---------------- kernel 1b: exact top-16 + softmax per batch row ----------------
__global__ void __launch_bounds__(256) emma_k1b(int* wsI, float* wsF)
{
  const int b = blockIdx.x, tid = threadIdx.x;
  __shared__ float s_sc[4096];
  __shared__ float s_rv[256]; __shared__ int s_ri[256];
  __shared__ float s_tv[16];
  for (int n=tid;n<4096;n+=256) s_sc[n] = wsF[OF_SCORES + b*4096 + n];
  __syncthreads();
  for (int j=0;j<16;j++){
    float bv = -3.0e38f; int bi = 0x7fffffff;
    for (int n=tid;n<4096;n+=256){
      float v = s_sc[n];
      if (v > bv || (v == bv && n < bi)) { bv=v; bi=n; }
    }
    s_rv[tid]=bv; s_ri[tid]=bi; __syncthreads();
    for (int st=128; st; st>>=1){
      if (tid<st){
        float v2=s_rv[tid+st]; int i2=s_ri[tid+st];
        if (v2 > s_rv[tid] || (v2==s_rv[tid] && i2 < s_ri[tid])) { s_rv[tid]=v2; s_ri[tid]=i2; }
      }
      __syncthreads();
    }
    if (tid==0){
      s_tv[j] = s_rv[0];
      wsI[2048 + b*16 + j] = s_ri[0];
      s_sc[s_ri[0]] = -3.0e38f;
    }
    __syncthreads();
  }
  if (tid==0){
    float mx = s_tv[0], sum=0.f, w[16];
    for (int j=0;j<16;j++){ w[j]=expf(s_tv[j]-mx); sum+=w[j]; }
    for (int j=0;j<16;j++) wsF[OF_TOPW + b*16 + j] = w[j]/sum;
  }
}

// ---------------- kernel 2: persistent trajectory kernel (steps 0..31) ----------------
__global__ void __launch_bounds__(256, 1) emma_k2(
    const int* tokens, const int* write_pos,
    const float* embed_W, const float* u_W1, const float* u_b1,
    const float* u_W2, const float* u_b2,
    const float* l_Wi, const float* l_Wh, const float* l_b,
    const float* l_Wti, const float* l_Wth, const float* l_bt,
    const float* h0, int* wsI, float* wsF)
{
  const int g = blockIdx.x & 7;      // group id (placement heuristic only)
  const int w = blockIdx.x >> 3;     // wg id within group, 0..31
  const int tid = threadIdx.x;
  int* flags = wsI + g*32;
  int epoch = 0;

  float* Z  = wsF + OF_Z;     // [2][32][512], buf0 = Z
  float* T  = wsF + OF_T;     // [32][1024]
  float* CP = wsF + OF_CP;    // [32][1024]
  float* G  = wsF + OF_G;     // [32][512]
  float* TA = wsF + OF_TAU;   // [32][512]
  float* H  = wsF + OF_H;     // [32][512]
  float* ZS = wsF + OF_ZS;
  float* HS = wsF + OF_HS;

  // ---- preamble: z=0, h=h0, c_pre for step 0 ----
  if (w < 16) {
    int idx = w*256 + tid;
    if (idx < 2048) { int r=idx>>9, c=idx&511; Z[(g*4+r)*512 + c] = 0.f; }
    else { int i2=idx-2048; int r=i2>>9, c=i2&511; H[(g*4+r)*512 + c] = h0[c]; }
  } else {
    int r = tid>>6, b = g*4+r;
    int c = (w-16)*64 + (tid&63);
    int tok = tokens[b*64 + 0];
    const float* xr = embed_W + (size_t)tok*256;
    float a0=0,a1=0,a2=0,a3=0;
    #pragma unroll 4
    for (int k=0;k<256;k+=4){
      float4 xv = *(const float4*)(xr + k);
      a0 += xv.x * u_W1[(512+k+0)*1024 + c];
      a1 += xv.y * u_W1[(512+k+1)*1024 + c];
      a2 += xv.z * u_W1[(512+k+2)*1024 + c];
      a3 += xv.w * u_W1[(512+k+3)*1024 + c];
    }
    CP[b*1024 + c] = u_b1[c] + ((a0+a1)+(a2+a3));
  }
  gbar(flags, w, epoch);

  for (int s=0;s<32;s++){
    for (int i=0;i<8;i++){
      float* zc = Z + (i&1)*16384;
      float* zn = Z + ((i&1)^1)*16384;
      // ---- phase A: t = tanh(z@W1z + c_pre); also pre-bias z_next = z + 0.5*b2
      if (tid < 128) {
        int r = tid>>5, b = g*4+r;
        int c = w*32 + (tid&31);
        const float* zr = zc + b*512;
        float a0=0,a1=0,a2=0,a3=0;
        #pragma unroll 4
        for (int k=0;k<512;k+=4){
          float4 zv = *(const float4*)(zr + k);
          a0 += zv.x * u_W1[(k+0)*1024 + c];
          a1 += zv.y * u_W1[(k+1)*1024 + c];
          a2 += zv.z * u_W1[(k+2)*1024 + c];
          a3 += zv.w * u_W1[(k+3)*1024 + c];
        }
        T[b*1024 + c] = tanhf(CP[b*1024 + c] + (a0+a1)+(a2+a3));
      }
      if (tid < 64) {
        int idx = w*64 + tid;
        int r = idx>>9, c = idx&511;
        int b = g*4+r;
        zn[b*512 + c] = zc[b*512 + c] + 0.5f*u_b2[c];
      }
      gbar(flags, w, epoch);
      // ---- phase B: z_next += 0.5*(t@W2), split-K 2-way across wgs via atomics
      if (tid < 128) {
        int r = tid>>5, b = g*4+r;
        int c2 = (w&15)*32 + (tid&31);
        int kh = w>>4;
        const float* tr = T + b*1024 + kh*512;
        const float* w2 = u_W2 + kh*512*512;
        float a0=0,a1=0,a2=0,a3=0;
        #pragma unroll 4
        for (int k=0;k<512;k+=4){
          float4 tv = *(const float4*)(tr + k);
          a0 += tv.x * w2[(k+0)*512 + c2];
          a1 += tv.y * w2[(k+1)*512 + c2];
          a2 += tv.z * w2[(k+2)*512 + c2];
          a3 += tv.w * w2[(k+3)*512 + c2];
        }
        atomicAdd(&zn[b*512 + c2], 0.5f*((a0+a1)+(a2+a3)));
      }
      if (i==7 && tid>=128) {  // init liquid pre-act buffers with biases for L1
        int idx = w*128 + (tid-128);
        if (idx < 2048){ int r=idx>>9, c=idx&511; G[(g*4+r)*512+c] = l_b[c]; }
        else { int i2=idx-2048; int r=i2>>9, c=i2&511; TA[(g*4+r)*512+c] = l_bt[c]; }
      }
      gbar(flags, w, epoch);
    }
    // ---- L1: liquid gate/tau pre-activations (z@Wi + h@Wh etc), split-K via atomics
    {
      int sub = tid>>7, l = tid&127;        // sub=0 -> gate, sub=1 -> tau
      int r = l>>5, b = g*4+r;
      int c2 = (w&15)*32 + (l&31);
      int kh = w>>4;                         // 0: z-part, 1: h-part
      const float* inrow = (kh==0) ? (Z + b*512) : (H + b*512);
      const float* W = sub ? (kh==0 ? l_Wti : l_Wth) : (kh==0 ? l_Wi : l_Wh);
      float a0=0,a1=0,a2=0,a3=0;
      #pragma unroll 4
      for (int k=0;k<512;k+=4){
        float4 iv = *(const float4*)(inrow + k);
        a0 += iv.x * W[(k+0)*512 + c2];
        a1 += iv.y * W[(k+1)*512 + c2];
        a2 += iv.z * W[(k+2)*512 + c2];
        a3 += iv.w * W[(k+3)*512 + c2];
      }
      atomicAdd(sub ? &TA[b*512+c2] : &G[b*512+c2], (a0+a1)+(a2+a3));
    }
    gbar(flags, w, epoch);
    // ---- L2: h update (+snapshots at write step) | c_pre for next step
    if (w < 16) {
      if (tid < 128) {
        int r = tid>>5, b = g*4+r;
        int c2 = w*32 + (tid&31);
        float gv = tanhf(G[b*512+c2]);
        float tv = softplusf_(TA[b*512+c2]) + 1.0f;
        float hv = H[b*512+c2];
        float hn = hv + (gv - hv)/tv;
        H[b*512+c2] = hn;
        if (write_pos[b] == s) { ZS[b*512+c2] = Z[b*512+c2]; HS[b*512+c2] = hn; }
      }
    } else if (s+1 < 32) {
      int r = tid>>6, b = g*4+r;
      int c = (w-16)*64 + (tid&63);
      int tok = tokens[b*64 + s+1];
      const float* xr = embed_W + (size_t)tok*256;
      float a0=0,a1=0,a2=0,a3=0;
      #pragma unroll 4
      for (int k=0;k<256;k+=4){
        float4 xv = *(const float4*)(xr + k);
        a0 += xv.x * u_W1[(512+k+0)*1024 + c];
        a1 += xv.y * u_W1[(512+k+1)*1024 + c];
        a2 += xv.z * u_W1[(512+k+2)*1024 + c];
        a3 += xv.w * u_W1[(512+k+3)*1024 + c];
      }
      CP[b*1024 + c] = u_b1[c] + ((a0+a1)+(a2+a3));
    }
    gbar(flags, w, epoch);
  }
}

// ---------------- kernel 3: v_pred + decay-weighted scatter into M ----------------
__global__ void __launch_bounds__(256) emma_k3(const float* z2v_W, const float* z2v_b,
                                               int* wsI, float* wsF)
{
  const int b = blockIdx.x, c = threadIdx.x;
  const float* zs = wsF + OF_ZS + b*512;
  const float* hs = wsF + OF_HS + b*512;
  float acc = z2v_b[c];
  for (int k=0;k<512;k++) acc += zs[k]*z2v_W[k*256 + c];
  for (int k=0;k<512;k++) acc += hs[k]*z2v_W[(512+k)*256 + c];
  __shared__ float red[256];
  red[c]=acc*acc; __syncthreads();
  for (int st=128; st; st>>=1){ if (c<st) red[c]+=red[c+st]; __syncthreads(); }
  float inv = 1.f/fmaxf(sqrtf(red[0]),1e-12f);
  float vp = acc*inv;
  float f = wsF[OF_DFAC + b];
  for (int j=0;j<16;j++){
    int slot = wsI[2048 + b*16 + j];
    float wj = wsF[OF_TOPW + b*16 + j];
    atomicAdd(&wsF[OF_M + (size_t)slot*256 + c], f*wj*vp);
  }
}

// ---------------- kernel 4: v_mem read, normalize, logits ----------------
__global__ void __launch_bounds__(256) emma_k4(const float* value_W, int* wsI, float* wsF,
                                               float* out)
{
  const int b = blockIdx.x, c = threadIdx.x;
  float m = 0.f;
  for (int j=0;j<16;j++){
    int slot = wsI[2048 + b*16 + j];
    m += wsF[OF_TOPW + b*16 + j] * wsF[OF_M + (size_t)slot*256 + c];
  }
  __shared__ float red[256];
  __shared__ float vn[256];
  red[c]=m*m; __syncthreads();
  for (int st=128; st; st>>=1){ if (c<st) red[c]+=red[c+st]; __syncthreads(); }
  float inv = 1.f/fmaxf(sqrtf(red[0]),1e-12f);
  vn[c] = m*inv;
  __syncthreads();
  float scale = wsF[OF_SCALE];
  for (int q=0;q<4;q++){
    int val = q*256 + c;
    const float* row = value_W + (size_t)val*256;
    float d0=0,d1=0,d2=0,d3=0;
    #pragma unroll 4
    for (int k=0;k<256;k+=4){
      float4 rv = *(const float4*)(row + k);
      d0 += vn[k+0]*rv.x; d1 += vn[k+1]*rv.y; d2 += vn[k+2]*rv.z; d3 += vn[k+3]*rv.w;
    }
    out[b*1024 + val] = scale * wsF[OF_RNV + val] * ((d0+d1)+(d2+d3));
  }
}

extern "C" void kernel_launch(void* const* d_in, const int* in_sizes, int n_in,
                              void* d_out, int out_size, void* d_ws, size_t ws_size,
                              hipStream_t stream)
{
  const int*   tokens    = (const int*)  d_in[0];
  const int*   key_ids   = (const int*)  d_in[1];
  const int*   write_pos = (const int*)  d_in[2];
  // d_in[3] query_pos, d_in[4] value_ids: provably unused by logits_main
  const float* embed_W   = (const float*)d_in[5];
  const float* key_W     = (const float*)d_in[6];
  const float* value_W   = (const float*)d_in[7];
  const float* u_W1      = (const float*)d_in[8];
  const float* u_b1      = (const float*)d_in[9];
  const float* u_W2      = (const float*)d_in[10];
  const float* u_b2      = (const float*)d_in[11];
  const float* l_Wi      = (const float*)d_in[12];
  const float* l_Wh      = (const float*)d_in[13];
  const float* l_b       = (const float*)d_in[14];
  const float* l_Wti     = (const float*)d_in[15];
  const float* l_Wth     = (const float*)d_in[16];
  const float* l_bt      = (const float*)d_in[17];
  const float* h0        = (const float*)d_in[18];
  const float* z2v_W     = (const float*)d_in[19];
  const float* z2v_b     = (const float*)d_in[20];
  const float* lsr       = (const float*)d_in[21];
  const float* slot_keys = (const float*)d_in[22];

  int*   wsI = (int*)d_ws;
  float* wsF = (float*)((char*)d_ws + 16384);
  float* out = (float*)d_out;

  hipLaunchKernelGGL(emma_k1a, dim3(325), dim3(256), 0, stream,
                     key_ids, write_pos, key_W, value_W, slot_keys, lsr, wsI, wsF);
  hipLaunchKernelGGL(emma_k1b, dim3(32), dim3(256), 0, stream, wsI, wsF);
  {
    void* args[] = { (void*)&tokens, (void*)&write_pos, (void*)&embed_W, (void*)&u_W1,
                     (void*)&u_b1, (void*)&u_W2, (void*)&u_b2, (void*)&l_Wi, (void*)&l_Wh,
                     (void*)&l_b, (void*)&l_Wti, (void*)&l_Wth, (void*)&l_bt, (void*)&h0,
                     (void*)&wsI, (void*)&wsF };
    hipLaunchCooperativeKernel(reinterpret_cast<void*>(emma_k2), dim3(256), dim3(256),
                               args, 0, stream);
  }
  hipLaunchKernelGGL(emma_k3, dim3(32), dim3(256), 0, stream, z2v_W, z2v_b, wsI, wsF);
  hipLaunchKernelGGL(emma_k4, dim3(32), dim3(256), 0, stream, value_W, wsI, wsF, out);
}

// Round 8
// 10845.057 us; speedup vs baseline: 1.5592x; 1.0035x over previous
//
#include <hip/hip_runtime.h>
#include <math.h>

// EMMA_38792144617759 v8 — v4 (passed, 10.9ms) with ONE change class: all k2
// weight reads go through pre-transposed col-major copies in ws (contiguous
// float4 per-thread streams instead of 4KB-strided scalar loads). v4's k2 was
// latency-bound on strided weight loads: 1.8GB FETCH (16x cacheline overfetch),
// VALUBusy 5.7%, 18us/phase. Everything else verbatim v4.

#define NGRP 8
#define WPG  32

// ---- workspace float offsets (wsF = d_ws + 16KB; first 16KB is int region) ----
#define OF_SCALE  0
#define OF_DFAC   32
#define OF_RNV    64
#define OF_TOPW   1088
#define OF_SCORES 1600      // 32*4096
#define OF_Z      132672    // 2*32*512 (double-buffered z)
#define OF_T      165440    // 32*1024
#define OF_CP     198208    // 32*1024
#define OF_G      230976    // 32*512
#define OF_TAU    247360    // 32*512
#define OF_H      263744    // 32*512
#define OF_ZS     280128    // 32*512
#define OF_HS     296512    // 32*512
#define OF_M      312896    // 4096*256
// transposed weight copies (filled by emma_tr before k2):
#define OF_W1ZT   1361472   // [1024 c][512 k]  = u_W1[k][c], k<512
#define OF_W1XT   1885760   // [1024 c][256 k]  = u_W1[512+k][c]
#define OF_W2T    2147904   // [512 c][1024 k]  = u_W2[k][c]
#define OF_LWIT   2672192   // [512 c][512 k]   = l_Wi[k][c]
#define OF_LWHT   2934336   // [512 c][512 k]   = l_Wh[k][c]
#define OF_LWTIT  3196480   // [512 c][512 k]   = l_Wti[k][c]
#define OF_LWTHT  3458624   // [512 c][512 k]   = l_Wth[k][c]
// end: 3720768 floats (~14.2MB) + 16KB ints
// wsI: [0..2048) barrier flags region (g*32+w used), [2048..2560) top_i

__device__ __forceinline__ float softplusf_(float x){ return x > 20.f ? x : log1pf(expf(x)); }

// Fence barrier (PROVEN in R4).
__device__ __forceinline__ void gbar(int* flags, int w, int& epoch){
  __syncthreads();
  epoch++;
  if (threadIdx.x == 0){
    __builtin_amdgcn_fence(__ATOMIC_RELEASE, "agent");
    __hip_atomic_store(&flags[w], epoch, __ATOMIC_RELAXED, __HIP_MEMORY_SCOPE_AGENT);
  }
  if (threadIdx.x < 32){
    while (__hip_atomic_load(&flags[threadIdx.x], __ATOMIC_RELAXED,
                             __HIP_MEMORY_SCOPE_AGENT) < epoch)
      __builtin_amdgcn_s_sleep(1);
    __builtin_amdgcn_fence(__ATOMIC_ACQUIRE, "agent");
  }
  __syncthreads();
}

// ---------------- kernel 0: generic row-major -> col-major transpose ----------------
// src is [R][C] row-major with C = 1<<shift; dst[c*R + r] = src[r*C + c].
// Coalesced reads, grid-stride; trivial by construction.
__global__ void __launch_bounds__(256) emma_tr(const float* src, float* dst,
                                               int shift, int total)
{
  const int R = total >> shift;
  const int cmask = (1 << shift) - 1;
  for (int idx = blockIdx.x*256 + threadIdx.x; idx < total; idx += gridDim.x*256){
    int r = idx >> shift, c = idx & cmask;
    dst[(size_t)c * R + r] = src[idx];
  }
}

// ---------------- kernel 1a: scores, M zero, value-row norms, misc (v4 verbatim) ----------------
__global__ void __launch_bounds__(256) emma_k1a(
    const int* key_ids, const int* write_pos,
    const float* key_W, const float* value_W, const float* slot_keys,
    const float* lsr, int* wsI, float* wsF)
{
  const int wg = blockIdx.x, tid = threadIdx.x;
  if (wg < 256) {
    const int b = wg >> 3, chunk = wg & 7;
    __shared__ __align__(16) float s_kv[256];
    __shared__ float red[256];
    float v = key_W[key_ids[b]*256 + tid];
    red[tid] = v*v; __syncthreads();
    for (int st=128; st; st>>=1){ if (tid<st) red[tid]+=red[tid+st]; __syncthreads(); }
    float inv = 1.f/fmaxf(sqrtf(red[0]), 1e-12f);
    s_kv[tid] = v*inv;
    __syncthreads();
    const int lane = tid & 63, wv = tid >> 6;
    float4 kv4 = *(const float4*)(s_kv + lane*4);
    for (int slot = chunk*512 + wv; slot < chunk*512 + 512; slot += 4){
      float4 sk = *(const float4*)(slot_keys + (size_t)slot*256 + lane*4);
      float p = kv4.x*sk.x + kv4.y*sk.y + kv4.z*sk.z + kv4.w*sk.w;
      #pragma unroll
      for (int m=32;m;m>>=1) p += __shfl_xor(p, m, 64);
      if (lane==0) wsF[OF_SCORES + b*4096 + slot] = p;
    }
  } else if (wg < 320) {
    const int j = wg - 256;
    for (int i=tid;i<16384;i+=256) wsF[OF_M + j*16384 + i] = 0.f;
  } else if (wg < 324) {
    const int row = (wg-320)*256 + tid;
    float ss=0.f; const float* r = value_W + (size_t)row*256;
    for (int k=0;k<256;k++){ float x=r[k]; ss += x*x; }
    wsF[OF_RNV + row] = 1.f/fmaxf(sqrtf(ss), 1e-12f);
  } else {
    for (int i=tid;i<2048;i+=256) wsI[i]=0;
    __shared__ int pres[32];
    if (tid<32){ int p=0; for (int bb=0;bb<32;bb++) if (write_pos[bb]==tid) p=1; pres[tid]=p; }
    __syncthreads();
    if (tid<32){
      int wp = write_pos[tid]; float f=1.f;
      for (int s=wp+1;s<32;s++) if (pres[s]) f *= 0.997f;
      wsF[OF_DFAC + tid] = f;
    }
    if (tid==0) wsF[OF_SCALE] = softplusf_(lsr[0]) + 1e-3f;
  }
}

// ---------------- kernel 1b: exact top-16 + softmax (v4 verbatim) ----------------
__global__ void __launch_bounds__(256) emma_k1b(int* wsI, float* wsF)
{
  const int b = blockIdx.x, tid = threadIdx.x;
  __shared__ float s_sc[4096];
  __shared__ float s_rv[256]; __shared__ int s_ri[256];
  __shared__ float s_tv[16];
  for (int n=tid;n<4096;n+=256) s_sc[n] = wsF[OF_SCORES + b*4096 + n];
  __syncthreads();
  for (int j=0;j<16;j++){
    float bv = -3.0e38f; int bi = 0x7fffffff;
    for (int n=tid;n<4096;n+=256){
      float v = s_sc[n];
      if (v > bv || (v == bv && n < bi)) { bv=v; bi=n; }
    }
    s_rv[tid]=bv; s_ri[tid]=bi; __syncthreads();
    for (int st=128; st; st>>=1){
      if (tid<st){
        float v2=s_rv[tid+st]; int i2=s_ri[tid+st];
        if (v2 > s_rv[tid] || (v2==s_rv[tid] && i2 < s_ri[tid])) { s_rv[tid]=v2; s_ri[tid]=i2; }
      }
      __syncthreads();
    }
    if (tid==0){
      s_tv[j] = s_rv[0];
      wsI[2048 + b*16 + j] = s_ri[0];
      s_sc[s_ri[0]] = -3.0e38f;
    }
    __syncthreads();
  }
  if (tid==0){
    float mx = s_tv[0], sum=0.f, w[16];
    for (int j=0;j<16;j++){ w[j]=expf(s_tv[j]-mx); sum+=w[j]; }
    for (int j=0;j<16;j++) wsF[OF_TOPW + b*16 + j] = w[j]/sum;
  }
}

// ---------------- kernel 2: persistent trajectory (v4 structure; transposed-weight addressing) ----------------
__global__ void __launch_bounds__(256, 1) emma_k2(
    const int* tokens, const int* write_pos,
    const float* embed_W, const float* u_b1, const float* u_b2,
    const float* l_b, const float* l_bt, const float* h0,
    int* wsI, float* wsF)
{
  const int g = blockIdx.x & 7;
  const int w = blockIdx.x >> 3;
  const int tid = threadIdx.x;
  int* flags = wsI + g*32;
  int epoch = 0;

  float* Z  = wsF + OF_Z;
  float* T  = wsF + OF_T;
  float* CP = wsF + OF_CP;
  float* G  = wsF + OF_G;
  float* TA = wsF + OF_TAU;
  float* H  = wsF + OF_H;
  float* ZS = wsF + OF_ZS;
  float* HS = wsF + OF_HS;
  const float* W1ZT = wsF + OF_W1ZT;
  const float* W1XT = wsF + OF_W1XT;
  const float* W2T  = wsF + OF_W2T;

  // ---- preamble: z=0, h=h0 | c_pre for step 0 ----
  if (w < 16) {
    int idx = w*256 + tid;
    if (idx < 2048) { int r=idx>>9, c=idx&511; Z[(g*4+r)*512 + c] = 0.f; }
    else { int i2=idx-2048; int r=i2>>9, c=i2&511; H[(g*4+r)*512 + c] = h0[c]; }
  } else {
    int r = tid>>6, b = g*4+r;
    int c = (w-16)*64 + (tid&63);
    int tok = tokens[b*64 + 0];
    const float* xr = embed_W + (size_t)tok*256;
    const float* wc = W1XT + (size_t)c*256;
    float a0=0,a1=0,a2=0,a3=0;
    #pragma unroll 4
    for (int k=0;k<256;k+=4){
      float4 xv = *(const float4*)(xr + k);
      float4 wv = *(const float4*)(wc + k);
      a0 += xv.x*wv.x; a1 += xv.y*wv.y; a2 += xv.z*wv.z; a3 += xv.w*wv.w;
    }
    CP[b*1024 + c] = u_b1[c] + ((a0+a1)+(a2+a3));
  }
  gbar(flags, w, epoch);

  for (int s=0;s<32;s++){
    for (int i=0;i<8;i++){
      float* zc = Z + (i&1)*16384;
      float* zn = Z + ((i&1)^1)*16384;
      // ---- phase A: t = tanh(z@W1z + c_pre); also pre-bias z_next = z + 0.5*b2
      if (tid < 128) {
        int r = tid>>5, b = g*4+r;
        int c = w*32 + (tid&31);
        const float* zr = zc + b*512;
        const float* wc = W1ZT + (size_t)c*512;
        float a0=0,a1=0,a2=0,a3=0;
        #pragma unroll 4
        for (int k=0;k<512;k+=4){
          float4 zv = *(const float4*)(zr + k);
          float4 wv = *(const float4*)(wc + k);
          a0 += zv.x*wv.x; a1 += zv.y*wv.y; a2 += zv.z*wv.z; a3 += zv.w*wv.w;
        }
        T[b*1024 + c] = tanhf(CP[b*1024 + c] + (a0+a1)+(a2+a3));
      }
      if (tid < 64) {
        int idx = w*64 + tid;
        int r = idx>>9, c = idx&511;
        int b = g*4+r;
        zn[b*512 + c] = zc[b*512 + c] + 0.5f*u_b2[c];
      }
      gbar(flags, w, epoch);
      // ---- phase B: z_next += 0.5*(t@W2), split-K 2-way across wgs via atomics
      if (tid < 128) {
        int r = tid>>5, b = g*4+r;
        int c2 = (w&15)*32 + (tid&31);
        int kh = w>>4;
        const float* tr = T + b*1024 + kh*512;
        const float* wc = W2T + (size_t)c2*1024 + kh*512;
        float a0=0,a1=0,a2=0,a3=0;
        #pragma unroll 4
        for (int k=0;k<512;k+=4){
          float4 tv = *(const float4*)(tr + k);
          float4 wv = *(const float4*)(wc + k);
          a0 += tv.x*wv.x; a1 += tv.y*wv.y; a2 += tv.z*wv.z; a3 += tv.w*wv.w;
        }
        atomicAdd(&zn[b*512 + c2], 0.5f*((a0+a1)+(a2+a3)));
      }
      if (i==7 && tid>=128) {  // init liquid pre-act buffers with biases for L1
        int idx = w*128 + (tid-128);
        if (idx < 2048){ int r=idx>>9, c=idx&511; G[(g*4+r)*512+c] = l_b[c]; }
        else { int i2=idx-2048; int r=i2>>9, c=i2&511; TA[(g*4+r)*512+c] = l_bt[c]; }
      }
      gbar(flags, w, epoch);
    }
    // ---- L1: liquid gate/tau pre-activations, split-K via atomics ----
    {
      int sub = tid>>7, l = tid&127;
      int r = l>>5, b = g*4+r;
      int c2 = (w&15)*32 + (l&31);
      int kh = w>>4;
      const float* inrow = (kh==0) ? (Z + b*512) : (H + b*512);
      const float* Wc = (sub ? (kh==0 ? wsF+OF_LWTIT : wsF+OF_LWTHT)
                             : (kh==0 ? wsF+OF_LWIT  : wsF+OF_LWHT)) + (size_t)c2*512;
      float a0=0,a1=0,a2=0,a3=0;
      #pragma unroll 4
      for (int k=0;k<512;k+=4){
        float4 iv = *(const float4*)(inrow + k);
        float4 wv = *(const float4*)(Wc + k);
        a0 += iv.x*wv.x; a1 += iv.y*wv.y; a2 += iv.z*wv.z; a3 += iv.w*wv.w;
      }
      atomicAdd(sub ? &TA[b*512+c2] : &G[b*512+c2], (a0+a1)+(a2+a3));
    }
    gbar(flags, w, epoch);
    // ---- L2: h update (+snapshots at write step) | c_pre for next step ----
    if (w < 16) {
      if (tid < 128) {
        int r = tid>>5, b = g*4+r;
        int c2 = w*32 + (tid&31);
        float gv = tanhf(G[b*512+c2]);
        float tv = softplusf_(TA[b*512+c2]) + 1.0f;
        float hv = H[b*512+c2];
        float hn = hv + (gv - hv)/tv;
        H[b*512+c2] = hn;
        if (write_pos[b] == s) { ZS[b*512+c2] = Z[b*512+c2]; HS[b*512+c2] = hn; }
      }
    } else if (s+1 < 32) {
      int r = tid>>6, b = g*4+r;
      int c = (w-16)*64 + (tid&63);
      int tok = tokens[b*64 + s+1];
      const float* xr = embed_W + (size_t)tok*256;
      const float* wc = W1XT + (size_t)c*256;
      float a0=0,a1=0,a2=0,a3=0;
      #pragma unroll 4
      for (int k=0;k<256;k+=4){
        float4 xv = *(const float4*)(xr + k);
        float4 wv = *(const float4*)(wc + k);
        a0 += xv.x*wv.x; a1 += xv.y*wv.y; a2 += xv.z*wv.z; a3 += xv.w*wv.w;
      }
      CP[b*1024 + c] = u_b1[c] + ((a0+a1)+(a2+a3));
    }
    gbar(flags, w, epoch);
  }
}

// ---------------- kernel 3: v_pred + decay-weighted scatter into M (v4 verbatim) ----------------
__global__ void __launch_bounds__(256) emma_k3(const float* z2v_W, const float* z2v_b,
                                               int* wsI, float* wsF)
{
  const int b = blockIdx.x, c = threadIdx.x;
  const float* zs = wsF + OF_ZS + b*512;
  const float* hs = wsF + OF_HS + b*512;
  float acc = z2v_b[c];
  for (int k=0;k<512;k++) acc += zs[k]*z2v_W[k*256 + c];
  for (int k=0;k<512;k++) acc += hs[k]*z2v_W[(512+k)*256 + c];
  __shared__ float red[256];
  red[c]=acc*acc; __syncthreads();
  for (int st=128; st; st>>=1){ if (c<st) red[c]+=red[c+st]; __syncthreads(); }
  float inv = 1.f/fmaxf(sqrtf(red[0]),1e-12f);
  float vp = acc*inv;
  float f = wsF[OF_DFAC + b];
  for (int j=0;j<16;j++){
    int slot = wsI[2048 + b*16 + j];
    float wj = wsF[OF_TOPW + b*16 + j];
    atomicAdd(&wsF[OF_M + (size_t)slot*256 + c], f*wj*vp);
  }
}

// ---------------- kernel 4: v_mem read, normalize, logits (v4 verbatim) ----------------
__global__ void __launch_bounds__(256) emma_k4(const float* value_W, int* wsI, float* wsF,
                                               float* out)
{
  const int b = blockIdx.x, c = threadIdx.x;
  float m = 0.f;
  for (int j=0;j<16;j++){
    int slot = wsI[2048 + b*16 + j];
    m += wsF[OF_TOPW + b*16 + j] * wsF[OF_M + (size_t)slot*256 + c];
  }
  __shared__ float red[256];
  __shared__ float vn[256];
  red[c]=m*m; __syncthreads();
  for (int st=128; st; st>>=1){ if (c<st) red[c]+=red[c+st]; __syncthreads(); }
  float inv = 1.f/fmaxf(sqrtf(red[0]),1e-12f);
  vn[c] = m*inv;
  __syncthreads();
  float scale = wsF[OF_SCALE];
  for (int q=0;q<4;q++){
    int val = q*256 + c;
    const float* row = value_W + (size_t)val*256;
    float d0=0,d1=0,d2=0,d3=0;
    #pragma unroll 4
    for (int k=0;k<256;k+=4){
      float4 rv = *(const float4*)(row + k);
      d0 += vn[k+0]*rv.x; d1 += vn[k+1]*rv.y; d2 += vn[k+2]*rv.z; d3 += vn[k+3]*rv.w;
    }
    out[b*1024 + val] = scale * wsF[OF_RNV + val] * ((d0+d1)+(d2+d3));
  }
}

extern "C" void kernel_launch(void* const* d_in, const int* in_sizes, int n_in,
                              void* d_out, int out_size, void* d_ws, size_t ws_size,
                              hipStream_t stream)
{
  const int*   tokens    = (const int*)  d_in[0];
  const int*   key_ids   = (const int*)  d_in[1];
  const int*   write_pos = (const int*)  d_in[2];
  const float* embed_W   = (const float*)d_in[5];
  const float* key_W     = (const float*)d_in[6];
  const float* value_W   = (const float*)d_in[7];
  const float* u_W1      = (const float*)d_in[8];
  const float* u_b1      = (const float*)d_in[9];
  const float* u_W2      = (const float*)d_in[10];
  const float* u_b2      = (const float*)d_in[11];
  const float* l_Wi      = (const float*)d_in[12];
  const float* l_Wh      = (const float*)d_in[13];
  const float* l_b       = (const float*)d_in[14];
  const float* l_Wti     = (const float*)d_in[15];
  const float* l_Wth     = (const float*)d_in[16];
  const float* l_bt      = (const float*)d_in[17];
  const float* h0        = (const float*)d_in[18];
  const float* z2v_W     = (const float*)d_in[19];
  const float* z2v_b     = (const float*)d_in[20];
  const float* lsr       = (const float*)d_in[21];
  const float* slot_keys = (const float*)d_in[22];

  int*   wsI = (int*)d_ws;
  float* wsF = (float*)((char*)d_ws + 16384);
  float* out = (float*)d_out;

  hipLaunchKernelGGL(emma_k1a, dim3(325), dim3(256), 0, stream,
                     key_ids, write_pos, key_W, value_W, slot_keys, lsr, wsI, wsF);
  hipLaunchKernelGGL(emma_k1b, dim3(32), dim3(256), 0, stream, wsI, wsF);
  // weight transposes (row-major [R][1<<shift] -> col-major):
  hipLaunchKernelGGL(emma_tr, dim3(512), dim3(256), 0, stream, u_W1,            wsF+OF_W1ZT, 10, 512*1024);
  hipLaunchKernelGGL(emma_tr, dim3(512), dim3(256), 0, stream, u_W1 + 512*1024, wsF+OF_W1XT, 10, 256*1024);
  hipLaunchKernelGGL(emma_tr, dim3(512), dim3(256), 0, stream, u_W2,            wsF+OF_W2T,   9, 1024*512);
  hipLaunchKernelGGL(emma_tr, dim3(512), dim3(256), 0, stream, l_Wi,            wsF+OF_LWIT,  9, 512*512);
  hipLaunchKernelGGL(emma_tr, dim3(512), dim3(256), 0, stream, l_Wh,            wsF+OF_LWHT,  9, 512*512);
  hipLaunchKernelGGL(emma_tr, dim3(512), dim3(256), 0, stream, l_Wti,           wsF+OF_LWTIT, 9, 512*512);
  hipLaunchKernelGGL(emma_tr, dim3(512), dim3(256), 0, stream, l_Wth,           wsF+OF_LWTHT, 9, 512*512);
  {
    void* args[] = { (void*)&tokens, (void*)&write_pos, (void*)&embed_W,
                     (void*)&u_b1, (void*)&u_b2, (void*)&l_b, (void*)&l_bt, (void*)&h0,
                     (void*)&wsI, (void*)&wsF };
    hipLaunchCooperativeKernel(reinterpret_cast<void*>(emma_k2), dim3(256), dim3(256),
                               args, 0, stream);
  }
  hipLaunchKernelGGL(emma_k3, dim3(32), dim3(256), 0, stream, z2v_W, z2v_b, wsI, wsF);
  hipLaunchKernelGGL(emma_k4, dim3(32), dim3(256), 0, stream, value_W, wsI, wsF, out);
}